// Round 1
// baseline (940.692 us; speedup 1.0000x reference)
//
#include <hip/hip_runtime.h>

// Problem constants: B=8, Cin=Cout=256, H=W=64, H2=W2=128, P=4 points.
#define NB   8
#define CH   256
#define HW0  4096    // 64*64
#define HW2  16384   // 128*128

// ---------------------------------------------------------------------------
// K1: dual GEMM on high_feat.  Per batch: C[n, m] = Wcat[n, k] * high[k, m]
//   n in [0,512): n<256 -> T channel n (W1a = W1[:, :256], no bias)
//                 n>=256 -> proc channel n-256 (Wf, + bf)
//   M = 4096 pixels, K = 256.
// Tile 64x64, 256 threads, 4x4 per thread, K-chunk 16.
// ---------------------------------------------------------------------------
__global__ __launch_bounds__(256) void k1_dual_gemm(
    const float* __restrict__ high, const float* __restrict__ W1,
    const float* __restrict__ Wf, const float* __restrict__ bfv,
    float* __restrict__ T, float* __restrict__ proc)
{
    const int b = blockIdx.z;
    const int n0 = blockIdx.y * 64;   // over N=512
    const int m0 = blockIdx.x * 64;   // over M=4096
    const int tid = threadIdx.x;
    const int tm = tid & 15, tn = tid >> 4;

    __shared__ float As[16][72];   // [k][n], 72 keeps float4 alignment
    __shared__ float Xs[16][64];   // [k][m]

    float acc[4][4] = {};
    const bool isT = (n0 < 256);

    const int lan = tid >> 2;        // 0..63  (A row in tile)
    const int lak = (tid & 3) * 4;   // 0,4,8,12
    const int lxk = tid >> 4;        // 0..15
    const int lxm = (tid & 15) * 4;  // 0..60
    const float* Xbase = high + (size_t)b * CH * HW0 + m0;

    for (int k0 = 0; k0 < 256; k0 += 16) {
        {
            int ng = n0 + lan;
            const float* ap = isT ? (W1 + (size_t)ng * 512 + k0 + lak)
                                  : (Wf + (size_t)(ng - 256) * 256 + k0 + lak);
            float4 a4 = *(const float4*)ap;
            As[lak + 0][lan] = a4.x;
            As[lak + 1][lan] = a4.y;
            As[lak + 2][lan] = a4.z;
            As[lak + 3][lan] = a4.w;
        }
        {
            float4 x4 = *(const float4*)(Xbase + (size_t)(k0 + lxk) * HW0 + lxm);
            *(float4*)&Xs[lxk][lxm] = x4;
        }
        __syncthreads();
        #pragma unroll
        for (int kk = 0; kk < 16; ++kk) {
            float4 a = *(const float4*)&As[kk][tn * 4];
            float4 x = *(const float4*)&Xs[kk][tm * 4];
            float av[4] = {a.x, a.y, a.z, a.w};
            float xv[4] = {x.x, x.y, x.z, x.w};
            #pragma unroll
            for (int i = 0; i < 4; ++i)
                #pragma unroll
                for (int j = 0; j < 4; ++j)
                    acc[i][j] += av[i] * xv[j];
        }
        __syncthreads();
    }

    const int m = m0 + tm * 4;
    #pragma unroll
    for (int i = 0; i < 4; ++i) {
        int ng = n0 + tn * 4 + i;
        if (isT) {
            float4 o = {acc[i][0], acc[i][1], acc[i][2], acc[i][3]};
            *(float4*)&T[((size_t)(b * CH + ng)) * HW0 + m] = o;
        } else {
            int c = ng - 256;
            float bias = bfv[c];
            float4 o = {acc[i][0] + bias, acc[i][1] + bias,
                        acc[i][2] + bias, acc[i][3] + bias};
            *(float4*)&proc[((size_t)(b * CH + c)) * HW0 + m] = o;
        }
    }
}

// ---------------------------------------------------------------------------
// K2: off_feat = relu( W1b @ low + up2x(T) + b1 ), written into d_out (scratch).
//   Per batch: N=256, M=16384, K=256.  up2x fused into the epilogue:
//   even coord 2k: taps (k-1 clamped, 0.25), (k, 0.75); odd 2k+1: (k,0.75),(k+1 clamped,0.25)
//   -- this matches jax.image.resize bilinear (half-pixel, renormalized edges).
// ---------------------------------------------------------------------------
__global__ __launch_bounds__(256) void k2_low_gemm(
    const float* __restrict__ low, const float* __restrict__ W1,
    const float* __restrict__ b1, const float* __restrict__ T,
    float* __restrict__ off_feat)
{
    const int b = blockIdx.z;
    const int n0 = blockIdx.y * 64;   // over N=256
    const int m0 = blockIdx.x * 64;   // over M=16384
    const int tid = threadIdx.x;
    const int tm = tid & 15, tn = tid >> 4;

    __shared__ float As[16][72];
    __shared__ float Xs[16][64];

    float acc[4][4] = {};
    const int lan = tid >> 2;
    const int lak = (tid & 3) * 4;
    const int lxk = tid >> 4;
    const int lxm = (tid & 15) * 4;
    const float* Xbase = low + (size_t)b * CH * HW2 + m0;

    for (int k0 = 0; k0 < 256; k0 += 16) {
        {
            int ng = n0 + lan;
            const float* ap = W1 + (size_t)ng * 512 + 256 + k0 + lak;  // W1b
            float4 a4 = *(const float4*)ap;
            As[lak + 0][lan] = a4.x;
            As[lak + 1][lan] = a4.y;
            As[lak + 2][lan] = a4.z;
            As[lak + 3][lan] = a4.w;
        }
        {
            float4 x4 = *(const float4*)(Xbase + (size_t)(k0 + lxk) * HW2 + lxm);
            *(float4*)&Xs[lxk][lxm] = x4;
        }
        __syncthreads();
        #pragma unroll
        for (int kk = 0; kk < 16; ++kk) {
            float4 a = *(const float4*)&As[kk][tn * 4];
            float4 x = *(const float4*)&Xs[kk][tm * 4];
            float av[4] = {a.x, a.y, a.z, a.w};
            float xv[4] = {x.x, x.y, x.z, x.w};
            #pragma unroll
            for (int i = 0; i < 4; ++i)
                #pragma unroll
                for (int j = 0; j < 4; ++j)
                    acc[i][j] += av[i] * xv[j];
        }
        __syncthreads();
    }

    // epilogue: y is uniform across the block (64-col tile inside a 128-wide row)
    const int y = m0 >> 7;
    int hk = y >> 1;
    int yA, yB; float wyA, wyB;
    if (y & 1) { yA = hk; yB = min(hk + 1, 63); wyA = 0.75f; wyB = 0.25f; }
    else       { yB = hk; yA = max(hk - 1, 0);  wyA = 0.25f; wyB = 0.75f; }

    #pragma unroll
    for (int i = 0; i < 4; ++i) {
        int ng = n0 + tn * 4 + i;
        const float* tb  = T + ((size_t)(b * CH + ng)) * HW0;
        const float* trA = tb + yA * 64;
        const float* trB = tb + yB * 64;
        float bias = b1[ng];
        float res[4];
        #pragma unroll
        for (int j = 0; j < 4; ++j) {
            int mg = m0 + tm * 4 + j;
            int x = mg & 127;
            int xk = x >> 1;
            int xA, xB; float wxA, wxB;
            if (x & 1) { xA = xk; xB = min(xk + 1, 63); wxA = 0.75f; wxB = 0.25f; }
            else       { xB = xk; xA = max(xk - 1, 0);  wxA = 0.25f; wxB = 0.75f; }
            float up = wyA * (wxA * trA[xA] + wxB * trA[xB])
                     + wyB * (wxA * trB[xA] + wxB * trB[xB]);
            res[j] = fmaxf(acc[i][j] + up + bias, 0.0f);
        }
        float4 o = {res[0], res[1], res[2], res[3]};
        *(float4*)&off_feat[((size_t)(b * CH + ng)) * HW2 + m0 + tm * 4] = o;
    }
}

// ---------------------------------------------------------------------------
// K3: offsets = conv3x3(off_feat, W2) + b2.  256 -> 8 channels, pad 1, zero-pad.
// Block: 256 threads = 2 rows x 128 cols.  W2 chunk staged in LDS (broadcast reads).
// ---------------------------------------------------------------------------
__global__ __launch_bounds__(256) void k3_conv3(
    const float* __restrict__ off_feat, const float* __restrict__ W2v,
    const float* __restrict__ b2v, float* __restrict__ offs)
{
    const int b = blockIdx.y;
    const int tid = threadIdx.x;
    const int x = tid & 127;
    const int y = blockIdx.x * 2 + (tid >> 7);

    __shared__ float w2s[32][8][9];   // [ci][o][j]
    float acc[8] = {};
    const float* fbase = off_feat + (size_t)b * CH * HW2;

    for (int c0 = 0; c0 < 256; c0 += 32) {
        __syncthreads();
        for (int i = tid; i < 32 * 8 * 9; i += 256) {
            int ci = i / 72, r = i % 72, o = r / 9, j = r % 9;
            w2s[ci][o][j] = W2v[o * 2304 + (c0 + ci) * 9 + j];
        }
        __syncthreads();
        for (int ci = 0; ci < 32; ++ci) {
            const float* p = fbase + (size_t)(c0 + ci) * HW2;
            float v[9];
            #pragma unroll
            for (int dy = -1; dy <= 1; ++dy) {
                int yy = y + dy;
                #pragma unroll
                for (int dx = -1; dx <= 1; ++dx) {
                    int xx = x + dx;
                    float val = 0.f;
                    if ((unsigned)yy < 128u && (unsigned)xx < 128u)
                        val = p[yy * 128 + xx];
                    v[(dy + 1) * 3 + dx + 1] = val;
                }
            }
            #pragma unroll
            for (int o = 0; o < 8; ++o) {
                float s = 0.f;
                #pragma unroll
                for (int j = 0; j < 9; ++j) s += w2s[ci][o][j] * v[j];
                acc[o] += s;
            }
        }
    }
    #pragma unroll
    for (int o = 0; o < 8; ++o)
        offs[(((size_t)b * 8 + o) * 128 + y) * 128 + x] = acc[o] + b2v[o];
}

// ---------------------------------------------------------------------------
// K4: deformable 4-point border-clamped bilinear sample of proc (64x64),
// averaged.  Grid positions computed once per pixel (shared across 256 ch).
// Block: (b, y, x-half); wave lanes span x -> coalesced proc/out access.
// ---------------------------------------------------------------------------
__global__ __launch_bounds__(256) void k4_sample(
    const float* __restrict__ offs, const float* __restrict__ proc,
    float* __restrict__ out)
{
    const int b = blockIdx.z;
    const int y = blockIdx.y;
    const int xt = blockIdx.x;   // 0..1
    const int tid = threadIdx.x;

    __shared__ int   sx0[4][64], sy0[4][64];
    __shared__ float sfx[4][64], sfy[4][64];

    if (tid < 64) {
        int x = xt * 64 + tid;
        float gxb = (2.0f * x) / 127.0f - 1.0f;
        float gyb = (2.0f * y) / 127.0f - 1.0f;
        const float* ob = offs + (size_t)b * 8 * HW2 + y * 128 + x;
        #pragma unroll
        for (int p = 0; p < 4; ++p) {
            float ox = ob[(2 * p) * HW2];
            float oy = ob[(2 * p + 1) * HW2];
            float gx = gxb + ox * (2.0f / 128.0f);
            float gy = gyb + oy * (2.0f / 128.0f);
            float gxp = fminf(fmaxf((gx + 1.0f) * 32.0f - 0.5f, 0.0f), 63.0f);
            float gyp = fminf(fmaxf((gy + 1.0f) * 32.0f - 0.5f, 0.0f), 63.0f);
            float x0 = floorf(gxp), y0f = floorf(gyp);
            sx0[p][tid] = (int)x0;
            sy0[p][tid] = (int)y0f;
            sfx[p][tid] = gxp - x0;
            sfy[p][tid] = gyp - y0f;
        }
    }
    __syncthreads();

    const int xl = tid & 63;
    const int cg = tid >> 6;
    const int x = xt * 64 + xl;

    int px0[4], py0[4]; float pfx[4], pfy[4];
    #pragma unroll
    for (int p = 0; p < 4; ++p) {
        px0[p] = sx0[p][xl]; py0[p] = sy0[p][xl];
        pfx[p] = sfx[p][xl]; pfy[p] = sfy[p][xl];
    }

    for (int c = cg; c < 256; c += 4) {
        const float* pb = proc + ((size_t)b * CH + c) * HW0;
        float acc = 0.f;
        #pragma unroll
        for (int p = 0; p < 4; ++p) {
            int x0 = px0[p], y0i = py0[p];
            int x1 = min(x0 + 1, 63), y1 = min(y0i + 1, 63);
            float fx = pfx[p], fy = pfy[p];
            float v00 = pb[y0i * 64 + x0];
            float v01 = pb[y0i * 64 + x1];
            float v10 = pb[y1 * 64 + x0];
            float v11 = pb[y1 * 64 + x1];
            float top = v00 + fx * (v01 - v00);
            float bot = v10 + fx * (v11 - v10);
            acc += top + fy * (bot - top);
        }
        out[(((size_t)b * CH + c) * 128 + y) * 128 + x] = acc * 0.25f;
    }
}

// ---------------------------------------------------------------------------
extern "C" void kernel_launch(void* const* d_in, const int* in_sizes, int n_in,
                              void* d_out, int out_size, void* d_ws, size_t ws_size,
                              hipStream_t stream) {
    const float* high = (const float*)d_in[0];
    const float* low  = (const float*)d_in[1];
    const float* W1   = (const float*)d_in[2];
    const float* b1   = (const float*)d_in[3];
    const float* W2v  = (const float*)d_in[4];
    const float* b2v  = (const float*)d_in[5];
    const float* Wf   = (const float*)d_in[6];
    const float* bfv  = (const float*)d_in[7];
    float* out = (float*)d_out;
    float* ws  = (float*)d_ws;

    float* T    = ws;                 // 8*256*4096  = 8388608 floats
    float* proc = ws + 8388608;       // 8*256*4096  = 8388608 floats
    float* offs = ws + 16777216;      // 8*8*16384   = 1048576 floats
    float* off_feat = out;            // d_out reused as scratch for off_feat

    // T = W1a@high (per-pixel), proc = Wf@high + bf
    k1_dual_gemm<<<dim3(64, 8, NB), 256, 0, stream>>>(high, W1, Wf, bfv, T, proc);
    // off_feat = relu(W1b@low + up2x(T) + b1)   [written to d_out]
    k2_low_gemm<<<dim3(256, 4, NB), 256, 0, stream>>>(low, W1, b1, T, off_feat);
    // offsets = conv3x3(off_feat, W2) + b2
    k3_conv3<<<dim3(64, NB), 256, 0, stream>>>(off_feat, W2v, b2v, offs);
    // out = mean over 4 deformable bilinear samples of proc
    k4_sample<<<dim3(2, 128, NB), 256, 0, stream>>>(offs, proc, out);
}

// Round 2
// 803.505 us; speedup vs baseline: 1.1707x; 1.1707x over previous
//
#include <hip/hip_runtime.h>

// Problem constants: B=8, Cin=Cout=256, H=W=64, H2=W2=128, P=4 points.
#define NB   8
#define CH   256
#define HW0  4096    // 64*64
#define HW2  16384   // 128*128
#define K3_CHUNKS 8

// ---------------------------------------------------------------------------
// K1: dual GEMM on high_feat.  Per batch: C[n, m] = Wcat[n, k] * high[k, m]
//   n in [0,512): n<256 -> T channel n (W1a = W1[:, :256], no bias)
//                 n>=256 -> proc channel n-256 (Wf, + bf)
// ---------------------------------------------------------------------------
__global__ __launch_bounds__(256) void k1_dual_gemm(
    const float* __restrict__ high, const float* __restrict__ W1,
    const float* __restrict__ Wf, const float* __restrict__ bfv,
    float* __restrict__ T, float* __restrict__ proc)
{
    const int b = blockIdx.z;
    const int n0 = blockIdx.y * 64;   // over N=512
    const int m0 = blockIdx.x * 64;   // over M=4096
    const int tid = threadIdx.x;
    const int tm = tid & 15, tn = tid >> 4;

    __shared__ float As[16][72];   // [k][n]
    __shared__ float Xs[16][64];   // [k][m]

    float acc[4][4] = {};
    const bool isT = (n0 < 256);

    const int lan = tid >> 2;        // 0..63
    const int lak = (tid & 3) * 4;   // 0,4,8,12
    const int lxk = tid >> 4;        // 0..15
    const int lxm = (tid & 15) * 4;  // 0..60
    const float* Xbase = high + (size_t)b * CH * HW0 + m0;

    for (int k0 = 0; k0 < 256; k0 += 16) {
        {
            int ng = n0 + lan;
            const float* ap = isT ? (W1 + (size_t)ng * 512 + k0 + lak)
                                  : (Wf + (size_t)(ng - 256) * 256 + k0 + lak);
            float4 a4 = *(const float4*)ap;
            As[lak + 0][lan] = a4.x;
            As[lak + 1][lan] = a4.y;
            As[lak + 2][lan] = a4.z;
            As[lak + 3][lan] = a4.w;
        }
        {
            float4 x4 = *(const float4*)(Xbase + (size_t)(k0 + lxk) * HW0 + lxm);
            *(float4*)&Xs[lxk][lxm] = x4;
        }
        __syncthreads();
        #pragma unroll
        for (int kk = 0; kk < 16; ++kk) {
            float4 a = *(const float4*)&As[kk][tn * 4];
            float4 x = *(const float4*)&Xs[kk][tm * 4];
            float av[4] = {a.x, a.y, a.z, a.w};
            float xv[4] = {x.x, x.y, x.z, x.w};
            #pragma unroll
            for (int i = 0; i < 4; ++i)
                #pragma unroll
                for (int j = 0; j < 4; ++j)
                    acc[i][j] += av[i] * xv[j];
        }
        __syncthreads();
    }

    const int m = m0 + tm * 4;
    #pragma unroll
    for (int i = 0; i < 4; ++i) {
        int ng = n0 + tn * 4 + i;
        if (isT) {
            float4 o = {acc[i][0], acc[i][1], acc[i][2], acc[i][3]};
            *(float4*)&T[((size_t)(b * CH + ng)) * HW0 + m] = o;
        } else {
            int c = ng - 256;
            float bias = bfv[c];
            float4 o = {acc[i][0] + bias, acc[i][1] + bias,
                        acc[i][2] + bias, acc[i][3] + bias};
            *(float4*)&proc[((size_t)(b * CH + c)) * HW0 + m] = o;
        }
    }
}

// ---------------------------------------------------------------------------
// K2: off_feat = relu( W1b @ low + up2x(T) + b1 ), written into d_out (scratch).
// ---------------------------------------------------------------------------
__global__ __launch_bounds__(256) void k2_low_gemm(
    const float* __restrict__ low, const float* __restrict__ W1,
    const float* __restrict__ b1, const float* __restrict__ T,
    float* __restrict__ off_feat)
{
    const int b = blockIdx.z;
    const int n0 = blockIdx.y * 64;   // over N=256
    const int m0 = blockIdx.x * 64;   // over M=16384
    const int tid = threadIdx.x;
    const int tm = tid & 15, tn = tid >> 4;

    __shared__ float As[16][72];
    __shared__ float Xs[16][64];

    float acc[4][4] = {};
    const int lan = tid >> 2;
    const int lak = (tid & 3) * 4;
    const int lxk = tid >> 4;
    const int lxm = (tid & 15) * 4;
    const float* Xbase = low + (size_t)b * CH * HW2 + m0;

    for (int k0 = 0; k0 < 256; k0 += 16) {
        {
            int ng = n0 + lan;
            const float* ap = W1 + (size_t)ng * 512 + 256 + k0 + lak;  // W1b
            float4 a4 = *(const float4*)ap;
            As[lak + 0][lan] = a4.x;
            As[lak + 1][lan] = a4.y;
            As[lak + 2][lan] = a4.z;
            As[lak + 3][lan] = a4.w;
        }
        {
            float4 x4 = *(const float4*)(Xbase + (size_t)(k0 + lxk) * HW2 + lxm);
            *(float4*)&Xs[lxk][lxm] = x4;
        }
        __syncthreads();
        #pragma unroll
        for (int kk = 0; kk < 16; ++kk) {
            float4 a = *(const float4*)&As[kk][tn * 4];
            float4 x = *(const float4*)&Xs[kk][tm * 4];
            float av[4] = {a.x, a.y, a.z, a.w};
            float xv[4] = {x.x, x.y, x.z, x.w};
            #pragma unroll
            for (int i = 0; i < 4; ++i)
                #pragma unroll
                for (int j = 0; j < 4; ++j)
                    acc[i][j] += av[i] * xv[j];
        }
        __syncthreads();
    }

    const int y = m0 >> 7;
    int hk = y >> 1;
    int yA, yB; float wyA, wyB;
    if (y & 1) { yA = hk; yB = min(hk + 1, 63); wyA = 0.75f; wyB = 0.25f; }
    else       { yB = hk; yA = max(hk - 1, 0);  wyA = 0.25f; wyB = 0.75f; }

    #pragma unroll
    for (int i = 0; i < 4; ++i) {
        int ng = n0 + tn * 4 + i;
        const float* tb  = T + ((size_t)(b * CH + ng)) * HW0;
        const float* trA = tb + yA * 64;
        const float* trB = tb + yB * 64;
        float bias = b1[ng];
        float res[4];
        #pragma unroll
        for (int j = 0; j < 4; ++j) {
            int mg = m0 + tm * 4 + j;
            int x = mg & 127;
            int xk = x >> 1;
            int xA, xB; float wxA, wxB;
            if (x & 1) { xA = xk; xB = min(xk + 1, 63); wxA = 0.75f; wxB = 0.25f; }
            else       { xB = xk; xA = max(xk - 1, 0);  wxA = 0.25f; wxB = 0.75f; }
            float up = wyA * (wxA * trA[xA] + wxB * trA[xB])
                     + wyB * (wxA * trB[xA] + wxB * trB[xB]);
            res[j] = fmaxf(acc[i][j] + up + bias, 0.0f);
        }
        float4 o = {res[0], res[1], res[2], res[3]};
        *(float4*)&off_feat[((size_t)(b * CH + ng)) * HW2 + m0 + tm * 4] = o;
    }
}

// ---------------------------------------------------------------------------
// K3: offsets += conv3x3(off_feat, W2)  (split-K over 8 channel chunks,
// atomicAdd accumulation into pre-zeroed offs; bias applied in K4).
// Block: 256 threads = 2 rows x 128 cols.  Grid: (64 row-tiles, 8 chunks, B).
// ---------------------------------------------------------------------------
__global__ __launch_bounds__(256) void k3_conv3(
    const float* __restrict__ off_feat, const float* __restrict__ W2v,
    float* __restrict__ offs)
{
    const int b = blockIdx.z;
    const int chunk = blockIdx.y;
    const int tid = threadIdx.x;
    const int x = tid & 127;
    const int y = blockIdx.x * 2 + (tid >> 7);
    const int c0 = chunk * 32;

    __shared__ float w2s[32][72];   // [ci][o*9+j]
    for (int i = tid; i < 32 * 72; i += 256) {
        int ci = i / 72, r = i % 72;
        w2s[ci][r] = W2v[(r / 9) * 2304 + (c0 + ci) * 9 + (r % 9)];
    }
    __syncthreads();

    float acc[8] = {};
    const float* fbase = off_feat + (size_t)b * CH * HW2;

    for (int ci = 0; ci < 32; ++ci) {
        const float* p = fbase + (size_t)(c0 + ci) * HW2;
        float v[9];
        #pragma unroll
        for (int dy = -1; dy <= 1; ++dy) {
            int yy = y + dy;
            #pragma unroll
            for (int dx = -1; dx <= 1; ++dx) {
                int xx = x + dx;
                float val = 0.f;
                if ((unsigned)yy < 128u && (unsigned)xx < 128u)
                    val = p[yy * 128 + xx];
                v[(dy + 1) * 3 + dx + 1] = val;
            }
        }
        #pragma unroll
        for (int o = 0; o < 8; ++o) {
            float s = 0.f;
            #pragma unroll
            for (int j = 0; j < 9; ++j) s += w2s[ci][o * 9 + j] * v[j];
            acc[o] += s;
        }
    }
    #pragma unroll
    for (int o = 0; o < 8; ++o)
        atomicAdd(&offs[(((size_t)b * 8 + o) * 128 + y) * 128 + x], acc[o]);
}

// ---------------------------------------------------------------------------
// K4: deformable 4-point border-clamped bilinear sample of proc (64x64),
// averaged.  b2 bias folded in when reading raw offsets.
// Grid: (2 x-halves, 128 rows, B*4 channel-quarters) -> 8192 blocks.
// ---------------------------------------------------------------------------
__global__ __launch_bounds__(256) void k4_sample(
    const float* __restrict__ offs, const float* __restrict__ b2v,
    const float* __restrict__ proc, float* __restrict__ out)
{
    const int bz = blockIdx.z;
    const int b = bz >> 2, cq = bz & 3;
    const int y = blockIdx.y;
    const int xt = blockIdx.x;   // 0..1
    const int tid = threadIdx.x;

    __shared__ int   sx0[4][64], sy0[4][64];
    __shared__ float sfx[4][64], sfy[4][64];

    if (tid < 64) {
        int x = xt * 64 + tid;
        float gxb = (2.0f * x) / 127.0f - 1.0f;
        float gyb = (2.0f * y) / 127.0f - 1.0f;
        const float* ob = offs + (size_t)b * 8 * HW2 + y * 128 + x;
        #pragma unroll
        for (int p = 0; p < 4; ++p) {
            float ox = ob[(2 * p) * HW2] + b2v[2 * p];
            float oy = ob[(2 * p + 1) * HW2] + b2v[2 * p + 1];
            float gx = gxb + ox * (2.0f / 128.0f);
            float gy = gyb + oy * (2.0f / 128.0f);
            float gxp = fminf(fmaxf((gx + 1.0f) * 32.0f - 0.5f, 0.0f), 63.0f);
            float gyp = fminf(fmaxf((gy + 1.0f) * 32.0f - 0.5f, 0.0f), 63.0f);
            float x0 = floorf(gxp), y0f = floorf(gyp);
            sx0[p][tid] = (int)x0;
            sy0[p][tid] = (int)y0f;
            sfx[p][tid] = gxp - x0;
            sfy[p][tid] = gyp - y0f;
        }
    }
    __syncthreads();

    const int xl = tid & 63;
    const int cl = tid >> 6;
    const int x = xt * 64 + xl;

    int px0[4], py0[4]; float pfx[4], pfy[4];
    #pragma unroll
    for (int p = 0; p < 4; ++p) {
        px0[p] = sx0[p][xl]; py0[p] = sy0[p][xl];
        pfx[p] = sfx[p][xl]; pfy[p] = sfy[p][xl];
    }

    #pragma unroll 4
    for (int i = 0; i < 16; ++i) {
        int c = cq * 64 + i * 4 + cl;
        const float* pb = proc + ((size_t)b * CH + c) * HW0;
        float acc = 0.f;
        #pragma unroll
        for (int p = 0; p < 4; ++p) {
            int x0 = px0[p], y0i = py0[p];
            int x1 = min(x0 + 1, 63), y1 = min(y0i + 1, 63);
            float fx = pfx[p], fy = pfy[p];
            float v00 = pb[y0i * 64 + x0];
            float v01 = pb[y0i * 64 + x1];
            float v10 = pb[y1 * 64 + x0];
            float v11 = pb[y1 * 64 + x1];
            float top = v00 + fx * (v01 - v00);
            float bot = v10 + fx * (v11 - v10);
            acc += top + fy * (bot - top);
        }
        out[(((size_t)b * CH + c) * 128 + y) * 128 + x] = acc * 0.25f;
    }
}

// ---------------------------------------------------------------------------
extern "C" void kernel_launch(void* const* d_in, const int* in_sizes, int n_in,
                              void* d_out, int out_size, void* d_ws, size_t ws_size,
                              hipStream_t stream) {
    const float* high = (const float*)d_in[0];
    const float* low  = (const float*)d_in[1];
    const float* W1   = (const float*)d_in[2];
    const float* b1   = (const float*)d_in[3];
    const float* W2v  = (const float*)d_in[4];
    const float* b2v  = (const float*)d_in[5];
    const float* Wf   = (const float*)d_in[6];
    const float* bfv  = (const float*)d_in[7];
    float* out = (float*)d_out;
    float* ws  = (float*)d_ws;

    float* T    = ws;                 // 8*256*4096  floats
    float* proc = ws + 8388608;       // 8*256*4096  floats
    float* offs = ws + 16777216;      // 8*8*16384   floats
    float* off_feat = out;            // d_out reused as scratch for off_feat

    // offs must start at zero (split-K atomic accumulation); ws is poisoned.
    hipMemsetAsync(offs, 0, (size_t)NB * 8 * HW2 * sizeof(float), stream);

    // T = W1a@high (per-pixel), proc = Wf@high + bf
    k1_dual_gemm<<<dim3(64, 8, NB), 256, 0, stream>>>(high, W1, Wf, bfv, T, proc);
    // off_feat = relu(W1b@low + up2x(T) + b1)   [written to d_out]
    k2_low_gemm<<<dim3(256, 4, NB), 256, 0, stream>>>(low, W1, b1, T, off_feat);
    // offs += conv3x3(off_feat, W2)   (bias folded into k4)
    k3_conv3<<<dim3(64, K3_CHUNKS, NB), 256, 0, stream>>>(off_feat, W2v, offs);
    // out = mean over 4 deformable bilinear samples of proc
    k4_sample<<<dim3(2, 128, NB * 4), 256, 0, stream>>>(offs, b2v, proc, out);
}

// Round 3
// 681.045 us; speedup vs baseline: 1.3812x; 1.1798x over previous
//
#include <hip/hip_runtime.h>
#include <stdint.h>

// Problem constants: B=8, Cin=Cout=256, H=W=64, H2=W2=128, P=4 points.
#define NB   8
#define CH   256
#define HW0  4096    // 64*64
#define HW2  16384   // 128*128
#define K3_CHUNKS 8

typedef __attribute__((ext_vector_type(8))) short short8;
typedef __attribute__((ext_vector_type(8))) unsigned short u16x8;
typedef __attribute__((ext_vector_type(4))) unsigned short u16x4;
typedef __attribute__((ext_vector_type(4))) float floatx4;

__device__ inline unsigned short f2bf(float f) {
    union { float f; uint32_t u; } v; v.f = f;
    return (unsigned short)((v.u + 0x7FFFu + ((v.u >> 16) & 1u)) >> 16);
}
__device__ inline float bf2f(unsigned short h) {
    union { uint32_t u; float f; } v; v.u = ((uint32_t)h) << 16;
    return v.f;
}

// ---------------------------------------------------------------------------
// ktrans: [B][256][M] f32  ->  [B][M][256] bf16   (transpose + convert)
// ---------------------------------------------------------------------------
__global__ __launch_bounds__(256) void ktrans(const float* __restrict__ src,
        unsigned short* __restrict__ dst, int M) {
    const int b = blockIdx.z, k0 = blockIdx.y * 32, m0 = blockIdx.x * 128;
    const int tid = threadIdx.x;
    __shared__ unsigned short tile[32][132];
    const float* s = src + ((size_t)b * CH + k0) * M + m0;
    for (int c = tid; c < 1024; c += 256) {
        int kk = c >> 5, mm = (c & 31) * 4;
        float4 v = *(const float4*)(s + (size_t)kk * M + mm);
        u16x4 o = { f2bf(v.x), f2bf(v.y), f2bf(v.z), f2bf(v.w) };
        *(u16x4*)&tile[kk][mm] = o;
    }
    __syncthreads();
    unsigned short* d = dst + ((size_t)b * M + m0) * CH + k0;
    for (int c = tid; c < 512; c += 256) {
        int mm = c >> 2, kc = (c & 3) * 8;
        u16x8 v;
        #pragma unroll
        for (int i = 0; i < 8; ++i) v[i] = tile[kc + i][mm];
        *(u16x8*)(d + (size_t)mm * CH + kc) = v;
    }
}

// ---------------------------------------------------------------------------
// kwconv: pack weights to bf16.  A1[512][256]: rows 0-255 = W1a, 256-511 = Wf.
// A2[256][256] = W1b.
// ---------------------------------------------------------------------------
__global__ __launch_bounds__(256) void kwconv(const float* __restrict__ W1,
        const float* __restrict__ Wf, unsigned short* __restrict__ A1,
        unsigned short* __restrict__ A2) {
    int i = blockIdx.x * 256 + threadIdx.x;
    if (i < 512 * 256) {
        int n = i >> 8, k = i & 255;
        float v = (n < 256) ? W1[n * 512 + k] : Wf[(size_t)(n - 256) * 256 + k];
        A1[i] = f2bf(v);
    }
    if (i < 256 * 256) {
        int n = i >> 8, k = i & 255;
        A2[i] = f2bf(W1[n * 512 + 256 + k]);
    }
}

// ---------------------------------------------------------------------------
// K1: dual MFMA GEMM:  D[n,m] = A1[n,:] . highT[m,:]   (k-contig both sides)
//   n<256 -> T[b][n][m] ; n>=256 -> proc[b][n-256][m] + bf
// Tile 128(n) x 128(m), 4 waves of 64x64, 16x16x32 bf16 MFMA.
// ---------------------------------------------------------------------------
__global__ __launch_bounds__(256) void k1_mfma(
    const unsigned short* __restrict__ highT,  // [B][4096][256]
    const unsigned short* __restrict__ A1,     // [512][256]
    const float* __restrict__ bfv,
    float* __restrict__ T, float* __restrict__ proc)
{
    const int b = blockIdx.z;
    const int m0 = blockIdx.x * 128;   // over 4096
    const int n0 = blockIdx.y * 128;   // over 512
    const int tid = threadIdx.x;
    __shared__ unsigned short As[128 * 40];
    __shared__ unsigned short Xs[128 * 40];
    const int lane = tid & 63, wid = tid >> 6;
    const int wn = (wid >> 1) * 64, wm = (wid & 1) * 64;
    const int l15 = lane & 15, quad = lane >> 4;

    floatx4 acc[4][4];
    #pragma unroll
    for (int i = 0; i < 4; ++i)
        #pragma unroll
        for (int j = 0; j < 4; ++j)
            acc[i][j] = (floatx4){0.f, 0.f, 0.f, 0.f};

    const unsigned short* Xg = highT + ((size_t)b * HW0 + m0) * CH;

    for (int k0 = 0; k0 < 256; k0 += 32) {
        for (int c = tid; c < 512; c += 256) {
            int row = c >> 2, kc = (c & 3) * 8;
            *(u16x8*)&As[row * 40 + kc] =
                *(const u16x8*)(A1 + (size_t)(n0 + row) * CH + k0 + kc);
            *(u16x8*)&Xs[row * 40 + kc] =
                *(const u16x8*)(Xg + (size_t)row * CH + k0 + kc);
        }
        __syncthreads();
        short8 af[4], bfr[4];
        #pragma unroll
        for (int i = 0; i < 4; ++i)
            af[i] = *(const short8*)&As[(wn + i * 16 + l15) * 40 + quad * 8];
        #pragma unroll
        for (int j = 0; j < 4; ++j)
            bfr[j] = *(const short8*)&Xs[(wm + j * 16 + l15) * 40 + quad * 8];
        #pragma unroll
        for (int i = 0; i < 4; ++i)
            #pragma unroll
            for (int j = 0; j < 4; ++j)
                acc[i][j] = __builtin_amdgcn_mfma_f32_16x16x32_bf16(
                    af[i], bfr[j], acc[i][j], 0, 0, 0);
        __syncthreads();
    }

    const bool isT = (n0 < 256);
    #pragma unroll
    for (int i = 0; i < 4; ++i) {
        int nb = n0 + wn + i * 16 + quad * 4;
        #pragma unroll
        for (int r = 0; r < 4; ++r) {
            int n = nb + r;
            #pragma unroll
            for (int j = 0; j < 4; ++j) {
                int m = m0 + wm + j * 16 + l15;
                float v = acc[i][j][r];
                if (isT) T[((size_t)b * CH + n) * HW0 + m] = v;
                else proc[((size_t)b * CH + n - 256) * HW0 + m] = v + bfv[n - 256];
            }
        }
    }
}

// ---------------------------------------------------------------------------
// K2: MFMA GEMM + fused upsample epilogue:
//   off_feat_bf16[n, y, x] = relu( A2[n,:].lowT[m,:] + up2x(T)[n,y,x] + b1[n] )
// Block covers one output row y (m0 = y*128).  Grid (128, 2, B).
// ---------------------------------------------------------------------------
__global__ __launch_bounds__(256) void k2_mfma(
    const unsigned short* __restrict__ lowT,   // [B][16384][256]
    const unsigned short* __restrict__ A2,     // [256][256]
    const float* __restrict__ b1, const float* __restrict__ T,
    unsigned short* __restrict__ off_feat)
{
    const int b = blockIdx.z;
    const int m0 = blockIdx.x * 128;   // over 16384; y = blockIdx.x
    const int n0 = blockIdx.y * 128;   // over 256
    const int tid = threadIdx.x;
    __shared__ unsigned short As[128 * 40];
    __shared__ unsigned short Xs[128 * 40];
    const int lane = tid & 63, wid = tid >> 6;
    const int wn = (wid >> 1) * 64, wm = (wid & 1) * 64;
    const int l15 = lane & 15, quad = lane >> 4;

    floatx4 acc[4][4];
    #pragma unroll
    for (int i = 0; i < 4; ++i)
        #pragma unroll
        for (int j = 0; j < 4; ++j)
            acc[i][j] = (floatx4){0.f, 0.f, 0.f, 0.f};

    const unsigned short* Xg = lowT + ((size_t)b * HW2 + m0) * CH;

    for (int k0 = 0; k0 < 256; k0 += 32) {
        for (int c = tid; c < 512; c += 256) {
            int row = c >> 2, kc = (c & 3) * 8;
            *(u16x8*)&As[row * 40 + kc] =
                *(const u16x8*)(A2 + (size_t)(n0 + row) * CH + k0 + kc);
            *(u16x8*)&Xs[row * 40 + kc] =
                *(const u16x8*)(Xg + (size_t)row * CH + k0 + kc);
        }
        __syncthreads();
        short8 af[4], bfr[4];
        #pragma unroll
        for (int i = 0; i < 4; ++i)
            af[i] = *(const short8*)&As[(wn + i * 16 + l15) * 40 + quad * 8];
        #pragma unroll
        for (int j = 0; j < 4; ++j)
            bfr[j] = *(const short8*)&Xs[(wm + j * 16 + l15) * 40 + quad * 8];
        #pragma unroll
        for (int i = 0; i < 4; ++i)
            #pragma unroll
            for (int j = 0; j < 4; ++j)
                acc[i][j] = __builtin_amdgcn_mfma_f32_16x16x32_bf16(
                    af[i], bfr[j], acc[i][j], 0, 0, 0);
        __syncthreads();
    }

    // epilogue: upsample taps. y uniform per block.
    const int y = blockIdx.x;
    int hk = y >> 1;
    int yA, yB; float wyA, wyB;
    if (y & 1) { yA = hk; yB = min(hk + 1, 63); wyA = 0.75f; wyB = 0.25f; }
    else       { yB = hk; yA = max(hk - 1, 0);  wyA = 0.25f; wyB = 0.75f; }

    int xA[4], xB[4]; float wxA[4], wxB[4];
    #pragma unroll
    for (int j = 0; j < 4; ++j) {
        int x = wm + j * 16 + l15;
        int xk = x >> 1;
        if (x & 1) { xA[j] = xk; xB[j] = min(xk + 1, 63); wxA[j] = 0.75f; wxB[j] = 0.25f; }
        else       { xB[j] = xk; xA[j] = max(xk - 1, 0);  wxA[j] = 0.25f; wxB[j] = 0.75f; }
    }

    #pragma unroll
    for (int i = 0; i < 4; ++i) {
        int nb = n0 + wn + i * 16 + quad * 4;
        #pragma unroll
        for (int r = 0; r < 4; ++r) {
            int n = nb + r;
            const float* tb  = T + ((size_t)b * CH + n) * HW0;
            const float* trA = tb + yA * 64;
            const float* trB = tb + yB * 64;
            float bias = b1[n];
            #pragma unroll
            for (int j = 0; j < 4; ++j) {
                float up = wyA * (wxA[j] * trA[xA[j]] + wxB[j] * trA[xB[j]])
                         + wyB * (wxA[j] * trB[xA[j]] + wxB[j] * trB[xB[j]]);
                float val = fmaxf(acc[i][j][r] + up + bias, 0.0f);
                off_feat[((size_t)b * CH + n) * HW2 + y * 128 + wm + j * 16 + l15] = f2bf(val);
            }
        }
    }
}

// ---------------------------------------------------------------------------
// K3: offsets += conv3x3(off_feat_bf16, W2)  (split-K over 8 channel chunks,
// atomicAdd into pre-zeroed offs; bias applied in K4).
// ---------------------------------------------------------------------------
__global__ __launch_bounds__(256) void k3_conv3(
    const unsigned short* __restrict__ off_feat, const float* __restrict__ W2v,
    float* __restrict__ offs)
{
    const int b = blockIdx.z;
    const int chunk = blockIdx.y;
    const int tid = threadIdx.x;
    const int x = tid & 127;
    const int y = blockIdx.x * 2 + (tid >> 7);
    const int c0 = chunk * 32;

    __shared__ float w2s[32][72];   // [ci][o*9+j]
    for (int i = tid; i < 32 * 72; i += 256) {
        int ci = i / 72, r = i % 72;
        w2s[ci][r] = W2v[(r / 9) * 2304 + (c0 + ci) * 9 + (r % 9)];
    }
    __syncthreads();

    float acc[8] = {};
    const unsigned short* fbase = off_feat + (size_t)b * CH * HW2;

    for (int ci = 0; ci < 32; ++ci) {
        const unsigned short* p = fbase + (size_t)(c0 + ci) * HW2;
        float v[9];
        #pragma unroll
        for (int dy = -1; dy <= 1; ++dy) {
            int yy = y + dy;
            #pragma unroll
            for (int dx = -1; dx <= 1; ++dx) {
                int xx = x + dx;
                float val = 0.f;
                if ((unsigned)yy < 128u && (unsigned)xx < 128u)
                    val = bf2f(p[yy * 128 + xx]);
                v[(dy + 1) * 3 + dx + 1] = val;
            }
        }
        #pragma unroll
        for (int o = 0; o < 8; ++o) {
            float s = 0.f;
            #pragma unroll
            for (int j = 0; j < 9; ++j) s += w2s[ci][o * 9 + j] * v[j];
            acc[o] += s;
        }
    }
    #pragma unroll
    for (int o = 0; o < 8; ++o)
        atomicAdd(&offs[(((size_t)b * 8 + o) * 128 + y) * 128 + x], acc[o]);
}

// ---------------------------------------------------------------------------
// K4: deformable 4-point border-clamped bilinear sample of proc (64x64),
// averaged.  b2 bias folded in when reading raw offsets.
// ---------------------------------------------------------------------------
__global__ __launch_bounds__(256) void k4_sample(
    const float* __restrict__ offs, const float* __restrict__ b2v,
    const float* __restrict__ proc, float* __restrict__ out)
{
    const int bz = blockIdx.z;
    const int b = bz >> 2, cq = bz & 3;
    const int y = blockIdx.y;
    const int xt = blockIdx.x;   // 0..1
    const int tid = threadIdx.x;

    __shared__ int   sx0[4][64], sy0[4][64];
    __shared__ float sfx[4][64], sfy[4][64];

    if (tid < 64) {
        int x = xt * 64 + tid;
        float gxb = (2.0f * x) / 127.0f - 1.0f;
        float gyb = (2.0f * y) / 127.0f - 1.0f;
        const float* ob = offs + (size_t)b * 8 * HW2 + y * 128 + x;
        #pragma unroll
        for (int p = 0; p < 4; ++p) {
            float ox = ob[(2 * p) * HW2] + b2v[2 * p];
            float oy = ob[(2 * p + 1) * HW2] + b2v[2 * p + 1];
            float gx = gxb + ox * (2.0f / 128.0f);
            float gy = gyb + oy * (2.0f / 128.0f);
            float gxp = fminf(fmaxf((gx + 1.0f) * 32.0f - 0.5f, 0.0f), 63.0f);
            float gyp = fminf(fmaxf((gy + 1.0f) * 32.0f - 0.5f, 0.0f), 63.0f);
            float x0 = floorf(gxp), y0f = floorf(gyp);
            sx0[p][tid] = (int)x0;
            sy0[p][tid] = (int)y0f;
            sfx[p][tid] = gxp - x0;
            sfy[p][tid] = gyp - y0f;
        }
    }
    __syncthreads();

    const int xl = tid & 63;
    const int cl = tid >> 6;
    const int x = xt * 64 + xl;

    int px0[4], py0[4]; float pfx[4], pfy[4];
    #pragma unroll
    for (int p = 0; p < 4; ++p) {
        px0[p] = sx0[p][xl]; py0[p] = sy0[p][xl];
        pfx[p] = sfx[p][xl]; pfy[p] = sfy[p][xl];
    }

    #pragma unroll 4
    for (int i = 0; i < 16; ++i) {
        int c = cq * 64 + i * 4 + cl;
        const float* pb = proc + ((size_t)b * CH + c) * HW0;
        float acc = 0.f;
        #pragma unroll
        for (int p = 0; p < 4; ++p) {
            int x0 = px0[p], y0i = py0[p];
            int x1 = min(x0 + 1, 63), y1 = min(y0i + 1, 63);
            float fx = pfx[p], fy = pfy[p];
            float v00 = pb[y0i * 64 + x0];
            float v01 = pb[y0i * 64 + x1];
            float v10 = pb[y1 * 64 + x0];
            float v11 = pb[y1 * 64 + x1];
            float top = v00 + fx * (v01 - v00);
            float bot = v10 + fx * (v11 - v10);
            acc += top + fy * (bot - top);
        }
        out[(((size_t)b * CH + c) * 128 + y) * 128 + x] = acc * 0.25f;
    }
}

// ---------------------------------------------------------------------------
extern "C" void kernel_launch(void* const* d_in, const int* in_sizes, int n_in,
                              void* d_out, int out_size, void* d_ws, size_t ws_size,
                              hipStream_t stream) {
    const float* high = (const float*)d_in[0];
    const float* low  = (const float*)d_in[1];
    const float* W1   = (const float*)d_in[2];
    const float* b1   = (const float*)d_in[3];
    const float* W2v  = (const float*)d_in[4];
    const float* b2v  = (const float*)d_in[5];
    const float* Wf   = (const float*)d_in[6];
    const float* bfv  = (const float*)d_in[7];
    float* out = (float*)d_out;
    float* ws  = (float*)d_ws;

    // ws layout (floats):
    float* T    = ws;                       // 8*256*4096  = 8388608
    float* proc = ws + 8388608;             // 8388608
    float* offs = ws + 16777216;            // 1048576
    unsigned short* highT = (unsigned short*)(ws + 17825792);  // 8388608 shorts
    unsigned short* A1 = highT + 8388608;   // 131072 shorts
    unsigned short* A2 = A1 + 131072;       // 65536 shorts  (total ~88.5 MB)

    // d_out (33554432 floats = 134 MB) doubles as scratch:
    unsigned short* lowT     = (unsigned short*)out;              // 33554432 shorts (67MB)
    unsigned short* off_feat = ((unsigned short*)out) + 33554432; // 33554432 shorts (67MB)

    // transpose+convert inputs to bf16 [b][m][k]
    ktrans<<<dim3(32, 8, NB), 256, 0, stream>>>(high, highT, HW0);
    ktrans<<<dim3(128, 8, NB), 256, 0, stream>>>(low, lowT, HW2);
    kwconv<<<dim3(512), 256, 0, stream>>>(W1, Wf, A1, A2);

    // offs must start at zero (split-K atomic accumulation)
    hipMemsetAsync(offs, 0, (size_t)NB * 8 * HW2 * sizeof(float), stream);

    // T = W1a@high, proc = Wf@high + bf     (bf16 MFMA)
    k1_mfma<<<dim3(32, 4, NB), 256, 0, stream>>>(highT, A1, bfv, T, proc);
    // off_feat = relu(W1b@low + up2x(T) + b1)  -> bf16 in d_out upper half
    k2_mfma<<<dim3(128, 2, NB), 256, 0, stream>>>(lowT, A2, b1, T, off_feat);
    // offs += conv3x3(off_feat, W2)
    k3_conv3<<<dim3(64, K3_CHUNKS, NB), 256, 0, stream>>>(off_feat, W2v, offs);
    // out = mean over 4 deformable bilinear samples of proc
    k4_sample<<<dim3(2, 128, NB * 4), 256, 0, stream>>>(offs, b2v, proc, out);
}